// Round 1
// baseline (443.190 us; speedup 1.0000x reference)
//
#include <hip/hip_runtime.h>

#define B_ 4
#define C_ 256
#define N_ 4096
#define D_ 32

typedef __bf16 bf16;
typedef __bf16 bf16x8 __attribute__((ext_vector_type(8)));
typedef float f32x4 __attribute__((ext_vector_type(4)));

// ---------------- kernel 1: 4x4 avgpool: x[B,C,256,256] -> xf[B,C,4096] (f32)
__global__ __launch_bounds__(256) void k_pool(const float* __restrict__ x,
                                              float* __restrict__ xf) {
  int i = blockIdx.x * 256 + threadIdx.x;              // 4,194,304 outputs
  int wp = i & 63, hp = (i >> 6) & 63, bc = i >> 12;   // bc = b*256 + c
  const float4* px = reinterpret_cast<const float4*>(x) + ((bc * 256 + hp * 4) * 64 + wp);
  float4 a0 = px[0], a1 = px[64], a2 = px[128], a3 = px[192];
  float s = a0.x + a0.y + a0.z + a0.w + a1.x + a1.y + a1.z + a1.w +
            a2.x + a2.y + a2.z + a2.w + a3.x + a3.y + a3.z + a3.w;
  xf[i] = s * 0.0625f;
}

// ---------------- kernel 2: q,k,v 1x1 convs from xf.
// Writes qt[b][n][32] bf16, kt[b][n][32] bf16 (transposed for MFMA A/B frags),
// v[b][c][n] bf16 (row-major along n, feeds PV B-frags directly).
__global__ __launch_bounds__(256) void k_qkv(const float* __restrict__ xf,
    const float* __restrict__ Wq, const float* __restrict__ bq,
    const float* __restrict__ Wk, const float* __restrict__ bk,
    const float* __restrict__ Wv, const float* __restrict__ bv,
    bf16* __restrict__ qt, bf16* __restrict__ kt, bf16* __restrict__ v) {
  __shared__ float xs[256][32];
  int tx = threadIdx.x, ty = threadIdx.y;              // (32,8)
  int b = blockIdx.x >> 7, n0 = (blockIdx.x & 127) * 32;
  const float* xfb = xf + (b << 8) * N_ + n0;
  for (int r = 0; r < 32; ++r) {
    int c = r * 8 + ty;
    xs[c][tx] = xfb[c * N_ + tx];
  }
  __syncthreads();
  for (int bb = 0; bb < 5; ++bb) {
    float acc[8]; const float* wr[8]; int rows[8];
    #pragma unroll
    for (int i = 0; i < 8; ++i) {
      int r = ty + 64 * bb + 8 * i; rows[i] = r;
      if (r < 32)      { wr[i] = Wq + (r << 8);        acc[i] = bq[r]; }
      else if (r < 64) { wr[i] = Wk + ((r - 32) << 8); acc[i] = bk[r - 32]; }
      else             { wr[i] = Wv + ((r - 64) << 8); acc[i] = bv[r - 64]; }
    }
    for (int c0 = 0; c0 < 256; c0 += 4) {
      float x0 = xs[c0][tx], x1 = xs[c0 + 1][tx], x2 = xs[c0 + 2][tx], x3 = xs[c0 + 3][tx];
      #pragma unroll
      for (int i = 0; i < 8; ++i) {
        float4 w4 = *reinterpret_cast<const float4*>(wr[i] + c0);
        acc[i] += w4.x * x0 + w4.y * x1 + w4.z * x2 + w4.w * x3;
      }
    }
    #pragma unroll
    for (int i = 0; i < 8; ++i) {
      int r = rows[i];
      if (r < 32)      qt[((b << 12) + n0 + tx) * D_ + r]        = (bf16)acc[i];
      else if (r < 64) kt[((b << 12) + n0 + tx) * D_ + (r - 32)] = (bf16)acc[i];
      else             v[((b << 8) + (r - 64)) * N_ + n0 + tx]   = (bf16)acc[i];
    }
  }
}

// ---------------- kernel 3: flash-style attention, bf16 MFMA.
// Block = 256 thr (4 waves), handles (b, 32 query tokens). No max-subtraction
// (|energy| < ~1). l = row-sum via MFMA against a ones B-fragment.
__global__ __launch_bounds__(256) void k_attn(const bf16* __restrict__ qt,
    const bf16* __restrict__ kt, const bf16* __restrict__ v,
    float* __restrict__ outs) {
  __shared__ bf16 p_s[32][264];          // P tile [tn][tm], +8 pad (528B rows)
  __shared__ float l_stage[4][32];
  __shared__ float l_s[32];
  int tid = threadIdx.x, wave = tid >> 6, l = tid & 63;
  int lg = l >> 4, ll = l & 15;
  int blk = blockIdx.x;
  int b  = (blk & 7) >> 1;                       // XCD x -> batch x/2 (L2 locality)
  int nt = ((blk >> 3) << 1) | (blk & 1);
  int n0 = nt * 32;

  const f32x4 fz = {0.f, 0.f, 0.f, 0.f};

  // A-frags for QK^T (A = Q^T [32tn x 32d]): row = tn = ll, k = d = lg*8+e
  bf16x8 aq[2];
  #pragma unroll
  for (int tnf = 0; tnf < 2; ++tnf)
    aq[tnf] = *reinterpret_cast<const bf16x8*>(
        qt + ((size_t)(b * N_ + n0 + tnf * 16 + ll)) * D_ + lg * 8);

  // ones B-frag: B[k][0] = 1, rest 0  -> D[tn][0] = row-sum of A
  bf16x8 onesf;
  {
    bf16 o = (bf16)(ll == 0 ? 1.0f : 0.0f);
    #pragma unroll
    for (int e = 0; e < 8; ++e) onesf[e] = o;
  }

  f32x4 acc[2][4];   // [tnf][cf] : out tile [32tn x 64c per wave]
  f32x4 lacc[2];
  #pragma unroll
  for (int a = 0; a < 2; ++a) {
    lacc[a] = fz;
    #pragma unroll
    for (int cf = 0; cf < 4; ++cf) acc[a][cf] = fz;
  }

  const int mw_off = wave * 64;   // phase A: this wave's tm range within tile
  const int cw0    = wave * 64;   // phase B: this wave's c range

  for (int t = 0; t < 16; ++t) {
    int m0 = t * 256;
    // ---- phase A: E = Q^T K for tm in [m0+mw_off, +64), write exp(E) to p_s
    #pragma unroll
    for (int tmf = 0; tmf < 4; ++tmf) {
      int mglob = m0 + mw_off + tmf * 16 + ll;
      bf16x8 bk8 = *reinterpret_cast<const bf16x8*>(
          kt + ((size_t)(b * N_ + mglob)) * D_ + lg * 8);
      #pragma unroll
      for (int tnf = 0; tnf < 2; ++tnf) {
        f32x4 e = __builtin_amdgcn_mfma_f32_16x16x32_bf16(aq[tnf], bk8, fz, 0, 0, 0);
        int col = mw_off + tmf * 16 + ll;   // D: row = tn = lg*4+r, col = tm = ll
        #pragma unroll
        for (int r = 0; r < 4; ++r) {
          float p = __expf(e[r]);
          p_s[tnf * 16 + lg * 4 + r][col] = (bf16)p;
        }
      }
    }
    __syncthreads();
    // ---- phase B: O += P V^T ; A = P[32tn x 256tm] from LDS, B from global v
    #pragma unroll
    for (int kk = 0; kk < 8; ++kk) {
      bf16x8 pa[2];
      #pragma unroll
      for (int tnf = 0; tnf < 2; ++tnf)
        pa[tnf] = *reinterpret_cast<const bf16x8*>(
            &p_s[tnf * 16 + ll][kk * 32 + lg * 8]);
      #pragma unroll
      for (int tnf = 0; tnf < 2; ++tnf)
        lacc[tnf] = __builtin_amdgcn_mfma_f32_16x16x32_bf16(pa[tnf], onesf, lacc[tnf], 0, 0, 0);
      #pragma unroll
      for (int cf = 0; cf < 4; ++cf) {
        int c = cw0 + cf * 16 + ll;
        bf16x8 bv8 = *reinterpret_cast<const bf16x8*>(
            v + ((size_t)((b << 8) + c)) * N_ + m0 + kk * 32 + lg * 8);
        acc[0][cf] = __builtin_amdgcn_mfma_f32_16x16x32_bf16(pa[0], bv8, acc[0][cf], 0, 0, 0);
        acc[1][cf] = __builtin_amdgcn_mfma_f32_16x16x32_bf16(pa[1], bv8, acc[1][cf], 0, 0, 0);
      }
    }
    __syncthreads();
  }

  // ---- reduce l across waves
  if (ll == 0) {
    #pragma unroll
    for (int tnf = 0; tnf < 2; ++tnf)
      #pragma unroll
      for (int r = 0; r < 4; ++r)
        l_stage[wave][tnf * 16 + lg * 4 + r] = lacc[tnf][r];
  }
  __syncthreads();
  if (tid < 32)
    l_s[tid] = l_stage[0][tid] + l_stage[1][tid] + l_stage[2][tid] + l_stage[3][tid];
  __syncthreads();

  // ---- normalize + write outs[b][c][n]
  #pragma unroll
  for (int tnf = 0; tnf < 2; ++tnf) {
    #pragma unroll
    for (int r = 0; r < 4; ++r) {
      int tn = tnf * 16 + lg * 4 + r;
      float inv = 1.0f / l_s[tn];
      #pragma unroll
      for (int cf = 0; cf < 4; ++cf) {
        int c = cw0 + cf * 16 + ll;
        outs[((size_t)((b << 8) + c)) * N_ + n0 + tn] = acc[tnf][cf][r] * inv;
      }
    }
  }
}

// ---------------- kernel 4: bilinear upsample x4 (half-pixel) + gamma residual
__global__ __launch_bounds__(256) void k_up(const float* __restrict__ outs,
    const float* __restrict__ x, const float* __restrict__ gamma,
    float* __restrict__ out) {
  int j = blockIdx.x * 256 + threadIdx.x;   // 16,777,216 (4 outputs each)
  int wq = j & 63, h = (j >> 6) & 255, bc = j >> 14;
  int th = 2 * h - 3;
  int h0 = th < 0 ? -1 : (th >> 3);
  float fh = (float)(th - 8 * h0) * 0.125f;
  int i0h = h0 < 0 ? 0 : h0;
  int i1h = h0 + 1 > 63 ? 63 : h0 + 1;
  const float* s0 = outs + ((size_t)(bc * 64 + i0h)) * 64;
  const float* s1 = outs + ((size_t)(bc * 64 + i1h)) * 64;
  float g = gamma[0];
  float r4[4];
  #pragma unroll
  for (int k2 = 0; k2 < 4; ++k2) {
    int w = wq * 4 + k2;
    int tw = 2 * w - 3;
    int w0 = tw < 0 ? -1 : (tw >> 3);
    float fw = (float)(tw - 8 * w0) * 0.125f;
    int i0 = w0 < 0 ? 0 : w0;
    int i1 = w0 + 1 > 63 ? 63 : w0 + 1;
    float a = s0[i0], bb = s0[i1], cc = s1[i0], dd = s1[i1];
    float top = a + fw * (bb - a);
    float bot = cc + fw * (dd - cc);
    r4[k2] = top + fh * (bot - top);
  }
  size_t o4 = (size_t)(bc * 256 + h) * 64 + wq;
  float4 xv = reinterpret_cast<const float4*>(x)[o4];
  float4 o;
  o.x = g * r4[0] + xv.x; o.y = g * r4[1] + xv.y;
  o.z = g * r4[2] + xv.z; o.w = g * r4[3] + xv.w;
  reinterpret_cast<float4*>(out)[o4] = o;
}

extern "C" void kernel_launch(void* const* d_in, const int* in_sizes, int n_in,
                              void* d_out, int out_size, void* d_ws, size_t ws_size,
                              hipStream_t stream) {
  const float* x     = (const float*)d_in[0];
  const float* Wq    = (const float*)d_in[1];
  const float* bq    = (const float*)d_in[2];
  const float* Wk    = (const float*)d_in[3];
  const float* bk    = (const float*)d_in[4];
  const float* Wv    = (const float*)d_in[5];
  const float* bv    = (const float*)d_in[6];
  const float* gamma = (const float*)d_in[7];
  float* out = (float*)d_out;

  char* ws = (char*)d_ws;
  float* xf   = (float*)(ws);                         // 16 MiB
  float* outs = (float*)(ws + (16u << 20));           // 16 MiB
  bf16*  v    = (bf16*) (ws + (32u << 20));           // 8 MiB
  bf16*  qt   = (bf16*) (ws + (40u << 20));           // 1 MiB
  bf16*  kt   = (bf16*) (ws + (41u << 20));           // 1 MiB

  hipLaunchKernelGGL(k_pool, dim3(16384), dim3(256), 0, stream, x, xf);
  hipLaunchKernelGGL(k_qkv,  dim3(512),   dim3(32, 8), 0, stream,
                     xf, Wq, bq, Wk, bk, Wv, bv, qt, kt, v);
  hipLaunchKernelGGL(k_attn, dim3(512),   dim3(256), 0, stream, qt, kt, v, outs);
  hipLaunchKernelGGL(k_up,   dim3(65536), dim3(256), 0, stream, outs, x, gamma, out);
}

// Round 2
// 307.205 us; speedup vs baseline: 1.4427x; 1.4427x over previous
//
#include <hip/hip_runtime.h>

#define B_ 4
#define C_ 256
#define N_ 4096
#define D_ 32

typedef __bf16 bf16;
typedef __bf16 bf16x4 __attribute__((ext_vector_type(4)));
typedef __bf16 bf16x8 __attribute__((ext_vector_type(8)));
typedef float f32x4 __attribute__((ext_vector_type(4)));

// ---------------- kernel 0: weight prep — concat W,b to bf16 wt[320][256], f32 bias[320]
__global__ __launch_bounds__(256) void k_prep(
    const float* __restrict__ Wq, const float* __restrict__ bq,
    const float* __restrict__ Wk, const float* __restrict__ bk,
    const float* __restrict__ Wv, const float* __restrict__ bv,
    bf16* __restrict__ wt, float* __restrict__ bias) {
  int r = blockIdx.x, t = threadIdx.x;
  const float* src; float bval;
  if (r < 32)      { src = Wq + (r << 8);        bval = bq[r]; }
  else if (r < 64) { src = Wk + ((r - 32) << 8); bval = bk[r - 32]; }
  else             { src = Wv + ((r - 64) << 8); bval = bv[r - 64]; }
  wt[(r << 8) + t] = (bf16)src[t];
  if (t == 0) bias[r] = bval;
}

// ---------------- kernel 1: fused avgpool(4x4) + q/k/v 1x1-conv GEMM (MFMA)
// Block = 256 thr (4 waves) handles (b, hp): 64 pooled tokens x all 320 out rows.
__global__ __launch_bounds__(256) void k_fused(const float* __restrict__ x,
    const bf16* __restrict__ wt, const float* __restrict__ bias,
    bf16* __restrict__ qt, bf16* __restrict__ kt, bf16* __restrict__ v) {
  __shared__ bf16 xsb[64][264];   // [n][c], +8 pad
  int tid = threadIdx.x, wave = tid >> 6, l = tid & 63;
  int lg = l >> 4, ll = l & 15;
  int b = blockIdx.x >> 6, hp = blockIdx.x & 63, n0 = hp * 64;

  // ---- phase 1: pool. wave w covers channels [w*64, w*64+64); lane l = token wp.
  const float4* x4 = reinterpret_cast<const float4*>(x) +
      ((size_t)((b * 256 + wave * 64) * 256 + hp * 4)) * 64 + l;
  for (int c0 = 0; c0 < 64; c0 += 4) {
    float s[4] = {0.f, 0.f, 0.f, 0.f};
    #pragma unroll
    for (int j = 0; j < 4; ++j) {
      const float4* p = x4 + (size_t)(c0 + j) * 16384;
      #pragma unroll
      for (int dh = 0; dh < 4; ++dh) {
        float4 a = p[dh * 64];
        s[j] += a.x + a.y + a.z + a.w;
      }
    }
    bf16x4 pk;
    #pragma unroll
    for (int j = 0; j < 4; ++j) pk[j] = (bf16)(s[j] * 0.0625f);
    *reinterpret_cast<bf16x4*>(&xsb[l][wave * 64 + c0]) = pk;
  }
  __syncthreads();

  // ---- phase 2: GEMM D[320 rows][64 n] = wt * xsb, K=256.
  // wave w owns rowblocks rb = w, w+4, w+8, w+12, w+16 (16 rows each).
  f32x4 acc[5][4];
  #pragma unroll
  for (int j = 0; j < 5; ++j)
    #pragma unroll
    for (int cb = 0; cb < 4; ++cb) acc[j][cb] = (f32x4){0.f, 0.f, 0.f, 0.f};

  for (int kk = 0; kk < 8; ++kk) {
    bf16x8 bfr[4];
    #pragma unroll
    for (int cb = 0; cb < 4; ++cb)
      bfr[cb] = *reinterpret_cast<const bf16x8*>(&xsb[cb * 16 + ll][kk * 32 + lg * 8]);
    #pragma unroll
    for (int j = 0; j < 5; ++j) {
      int rb = wave + j * 4;
      bf16x8 afr = *reinterpret_cast<const bf16x8*>(
          wt + ((size_t)(rb * 16 + ll)) * 256 + kk * 32 + lg * 8);
      #pragma unroll
      for (int cb = 0; cb < 4; ++cb)
        acc[j][cb] = __builtin_amdgcn_mfma_f32_16x16x32_bf16(afr, bfr[cb], acc[j][cb], 0, 0, 0);
    }
  }

  // ---- epilogue: + bias, write qt[b][n][32], kt[b][n][32], v[b][c][n]
  #pragma unroll
  for (int j = 0; j < 5; ++j) {
    int rb = wave + j * 4;
    int row0 = rb * 16 + lg * 4;
    float4 b4 = *reinterpret_cast<const float4*>(bias + row0);
    #pragma unroll
    for (int cb = 0; cb < 4; ++cb) {
      int n = n0 + cb * 16 + ll;
      float v0 = acc[j][cb][0] + b4.x, v1 = acc[j][cb][1] + b4.y;
      float v2 = acc[j][cb][2] + b4.z, v3 = acc[j][cb][3] + b4.w;
      if (row0 < 32) {
        bf16x4 pk = {(bf16)v0, (bf16)v1, (bf16)v2, (bf16)v3};
        *reinterpret_cast<bf16x4*>(qt + ((size_t)(b * N_ + n)) * D_ + row0) = pk;
      } else if (row0 < 64) {
        bf16x4 pk = {(bf16)v0, (bf16)v1, (bf16)v2, (bf16)v3};
        *reinterpret_cast<bf16x4*>(kt + ((size_t)(b * N_ + n)) * D_ + row0 - 32) = pk;
      } else {
        int c = row0 - 64;
        v[((size_t)(b * 256 + c + 0)) * N_ + n] = (bf16)v0;
        v[((size_t)(b * 256 + c + 1)) * N_ + n] = (bf16)v1;
        v[((size_t)(b * 256 + c + 2)) * N_ + n] = (bf16)v2;
        v[((size_t)(b * 256 + c + 3)) * N_ + n] = (bf16)v3;
      }
    }
  }
}

// ---------------- kernel 3: flash-style attention, bf16 MFMA.
__global__ __launch_bounds__(256) void k_attn(const bf16* __restrict__ qt,
    const bf16* __restrict__ kt, const bf16* __restrict__ v,
    float* __restrict__ outs) {
  __shared__ bf16 p_s[32][264];          // P tile [tn][tm], +8 pad
  __shared__ float l_stage[4][32];
  __shared__ float l_s[32];
  int tid = threadIdx.x, wave = tid >> 6, l = tid & 63;
  int lg = l >> 4, ll = l & 15;
  int blk = blockIdx.x;
  int b  = (blk & 7) >> 1;                       // XCD -> batch (L2 locality)
  int nt = ((blk >> 3) << 1) | (blk & 1);
  int n0 = nt * 32;

  const f32x4 fz = {0.f, 0.f, 0.f, 0.f};

  bf16x8 aq[2];
  #pragma unroll
  for (int tnf = 0; tnf < 2; ++tnf)
    aq[tnf] = *reinterpret_cast<const bf16x8*>(
        qt + ((size_t)(b * N_ + n0 + tnf * 16 + ll)) * D_ + lg * 8);

  bf16x8 onesf;
  {
    bf16 o = (bf16)(ll == 0 ? 1.0f : 0.0f);
    #pragma unroll
    for (int e = 0; e < 8; ++e) onesf[e] = o;
  }

  f32x4 acc[2][4];
  f32x4 lacc[2];
  #pragma unroll
  for (int a = 0; a < 2; ++a) {
    lacc[a] = fz;
    #pragma unroll
    for (int cf = 0; cf < 4; ++cf) acc[a][cf] = fz;
  }

  const int mw_off = wave * 64;
  const int cw0    = wave * 64;

  for (int t = 0; t < 16; ++t) {
    int m0 = t * 256;
    #pragma unroll
    for (int tmf = 0; tmf < 4; ++tmf) {
      int mglob = m0 + mw_off + tmf * 16 + ll;
      bf16x8 bk8 = *reinterpret_cast<const bf16x8*>(
          kt + ((size_t)(b * N_ + mglob)) * D_ + lg * 8);
      #pragma unroll
      for (int tnf = 0; tnf < 2; ++tnf) {
        f32x4 e = __builtin_amdgcn_mfma_f32_16x16x32_bf16(aq[tnf], bk8, fz, 0, 0, 0);
        int col = mw_off + tmf * 16 + ll;
        #pragma unroll
        for (int r = 0; r < 4; ++r) {
          float p = __expf(e[r]);
          p_s[tnf * 16 + lg * 4 + r][col] = (bf16)p;
        }
      }
    }
    __syncthreads();
    #pragma unroll
    for (int kk = 0; kk < 8; ++kk) {
      bf16x8 pa[2];
      #pragma unroll
      for (int tnf = 0; tnf < 2; ++tnf)
        pa[tnf] = *reinterpret_cast<const bf16x8*>(
            &p_s[tnf * 16 + ll][kk * 32 + lg * 8]);
      #pragma unroll
      for (int tnf = 0; tnf < 2; ++tnf)
        lacc[tnf] = __builtin_amdgcn_mfma_f32_16x16x32_bf16(pa[tnf], onesf, lacc[tnf], 0, 0, 0);
      #pragma unroll
      for (int cf = 0; cf < 4; ++cf) {
        int c = cw0 + cf * 16 + ll;
        bf16x8 bv8 = *reinterpret_cast<const bf16x8*>(
            v + ((size_t)((b << 8) + c)) * N_ + m0 + kk * 32 + lg * 8);
        acc[0][cf] = __builtin_amdgcn_mfma_f32_16x16x32_bf16(pa[0], bv8, acc[0][cf], 0, 0, 0);
        acc[1][cf] = __builtin_amdgcn_mfma_f32_16x16x32_bf16(pa[1], bv8, acc[1][cf], 0, 0, 0);
      }
    }
    __syncthreads();
  }

  if (ll == 0) {
    #pragma unroll
    for (int tnf = 0; tnf < 2; ++tnf)
      #pragma unroll
      for (int r = 0; r < 4; ++r)
        l_stage[wave][tnf * 16 + lg * 4 + r] = lacc[tnf][r];
  }
  __syncthreads();
  if (tid < 32)
    l_s[tid] = l_stage[0][tid] + l_stage[1][tid] + l_stage[2][tid] + l_stage[3][tid];
  __syncthreads();

  #pragma unroll
  for (int tnf = 0; tnf < 2; ++tnf) {
    #pragma unroll
    for (int r = 0; r < 4; ++r) {
      int tn = tnf * 16 + lg * 4 + r;
      float inv = 1.0f / l_s[tn];
      #pragma unroll
      for (int cf = 0; cf < 4; ++cf) {
        int c = cw0 + cf * 16 + ll;
        outs[((size_t)((b << 8) + c)) * N_ + n0 + tn] = acc[tnf][cf][r] * inv;
      }
    }
  }
}

// ---------------- kernel 4: bilinear upsample x4 + gamma residual
__global__ __launch_bounds__(256) void k_up(const float* __restrict__ outs,
    const float* __restrict__ x, const float* __restrict__ gamma,
    float* __restrict__ out) {
  int j = blockIdx.x * 256 + threadIdx.x;
  int wq = j & 63, h = (j >> 6) & 255, bc = j >> 14;
  int th = 2 * h - 3;
  int h0 = th < 0 ? -1 : (th >> 3);
  float fh = (float)(th - 8 * h0) * 0.125f;
  int i0h = h0 < 0 ? 0 : h0;
  int i1h = h0 + 1 > 63 ? 63 : h0 + 1;
  const float* s0 = outs + ((size_t)(bc * 64 + i0h)) * 64;
  const float* s1 = outs + ((size_t)(bc * 64 + i1h)) * 64;
  float g = gamma[0];
  float r4[4];
  #pragma unroll
  for (int k2 = 0; k2 < 4; ++k2) {
    int w = wq * 4 + k2;
    int tw = 2 * w - 3;
    int w0 = tw < 0 ? -1 : (tw >> 3);
    float fw = (float)(tw - 8 * w0) * 0.125f;
    int i0 = w0 < 0 ? 0 : w0;
    int i1 = w0 + 1 > 63 ? 63 : w0 + 1;
    float a = s0[i0], bb = s0[i1], cc = s1[i0], dd = s1[i1];
    float top = a + fw * (bb - a);
    float bot = cc + fw * (dd - cc);
    r4[k2] = top + fh * (bot - top);
  }
  size_t o4 = (size_t)(bc * 256 + h) * 64 + wq;
  float4 xv = reinterpret_cast<const float4*>(x)[o4];
  float4 o;
  o.x = g * r4[0] + xv.x; o.y = g * r4[1] + xv.y;
  o.z = g * r4[2] + xv.z; o.w = g * r4[3] + xv.w;
  reinterpret_cast<float4*>(out)[o4] = o;
}

extern "C" void kernel_launch(void* const* d_in, const int* in_sizes, int n_in,
                              void* d_out, int out_size, void* d_ws, size_t ws_size,
                              hipStream_t stream) {
  const float* x     = (const float*)d_in[0];
  const float* Wq    = (const float*)d_in[1];
  const float* bq    = (const float*)d_in[2];
  const float* Wk    = (const float*)d_in[3];
  const float* bk    = (const float*)d_in[4];
  const float* Wv    = (const float*)d_in[5];
  const float* bv    = (const float*)d_in[6];
  const float* gamma = (const float*)d_in[7];
  float* out = (float*)d_out;

  char* ws = (char*)d_ws;
  float* outs = (float*)(ws);                         // 16 MiB
  bf16*  v    = (bf16*) (ws + (16u << 20));           // 8 MiB
  bf16*  qt   = (bf16*) (ws + (24u << 20));           // 1 MiB
  bf16*  kt   = (bf16*) (ws + (25u << 20));           // 1 MiB
  bf16*  wt   = (bf16*) (ws + (26u << 20));           // 160 KiB
  float* bias = (float*)(ws + (27u << 20));           // 1.25 KiB

  hipLaunchKernelGGL(k_prep,  dim3(320),   dim3(256), 0, stream,
                     Wq, bq, Wk, bk, Wv, bv, wt, bias);
  hipLaunchKernelGGL(k_fused, dim3(256),   dim3(256), 0, stream,
                     x, wt, bias, qt, kt, v);
  hipLaunchKernelGGL(k_attn,  dim3(512),   dim3(256), 0, stream, qt, kt, v, outs);
  hipLaunchKernelGGL(k_up,    dim3(65536), dim3(256), 0, stream, outs, x, gamma, out);
}

// Round 3
// 298.236 us; speedup vs baseline: 1.4860x; 1.0301x over previous
//
#include <hip/hip_runtime.h>

#define B_ 4
#define C_ 256
#define N_ 4096
#define D_ 32

typedef __bf16 bf16;
typedef __bf16 bf16x4 __attribute__((ext_vector_type(4)));
typedef __bf16 bf16x8 __attribute__((ext_vector_type(8)));
typedef float f32x4 __attribute__((ext_vector_type(4)));

// ---------------- kernel 0: weight prep — concat W,b to bf16 wt[320][256], f32 bias[320]
__global__ __launch_bounds__(256) void k_prep(
    const float* __restrict__ Wq, const float* __restrict__ bq,
    const float* __restrict__ Wk, const float* __restrict__ bk,
    const float* __restrict__ Wv, const float* __restrict__ bv,
    bf16* __restrict__ wt, float* __restrict__ bias) {
  int r = blockIdx.x, t = threadIdx.x;
  const float* src; float bval;
  if (r < 32)      { src = Wq + (r << 8);        bval = bq[r]; }
  else if (r < 64) { src = Wk + ((r - 32) << 8); bval = bk[r - 32]; }
  else             { src = Wv + ((r - 64) << 8); bval = bv[r - 64]; }
  wt[(r << 8) + t] = (bf16)src[t];
  if (t == 0) bias[r] = bval;
}

// ---------------- kernel 1: fused avgpool(4x4) + q/k/v 1x1-conv GEMM (MFMA)
// Block = 512 thr (8 waves) handles (b, hp): 64 pooled tokens x all 320 out rows.
__global__ __launch_bounds__(512) void k_fused(const float* __restrict__ x,
    const bf16* __restrict__ wt, const float* __restrict__ bias,
    bf16* __restrict__ qt, bf16* __restrict__ kt, bf16* __restrict__ v) {
  __shared__ bf16 xsb[64][264];   // [n][c], +8 pad
  int tid = threadIdx.x, wave = tid >> 6, l = tid & 63;
  int lg = l >> 4, ll = l & 15;
  int b = blockIdx.x >> 6, hp = blockIdx.x & 63, n0 = hp * 64;

  // ---- phase 1: pool. wave w covers channels [w*32, w*32+32); lane l = token wp.
  const float4* x4 = reinterpret_cast<const float4*>(x) +
      ((size_t)((b * 256 + wave * 32) * 256 + hp * 4)) * 64 + l;
  for (int c0 = 0; c0 < 32; c0 += 4) {
    float s[4] = {0.f, 0.f, 0.f, 0.f};
    #pragma unroll
    for (int j = 0; j < 4; ++j) {
      const float4* p = x4 + (size_t)(c0 + j) * 16384;
      #pragma unroll
      for (int dh = 0; dh < 4; ++dh) {
        float4 a = p[dh * 64];
        s[j] += a.x + a.y + a.z + a.w;
      }
    }
    bf16x4 pk;
    #pragma unroll
    for (int j = 0; j < 4; ++j) pk[j] = (bf16)(s[j] * 0.0625f);
    *reinterpret_cast<bf16x4*>(&xsb[l][wave * 32 + c0]) = pk;
  }
  __syncthreads();

  // ---- phase 2: GEMM D[320 rows][64 n] = wt * xsb, K=256.
  // 20 rowblocks of 16; wave w owns rb = w, w+8, and (w<4) w+16.
  f32x4 acc[3][4];
  #pragma unroll
  for (int j = 0; j < 3; ++j)
    #pragma unroll
    for (int cb = 0; cb < 4; ++cb) acc[j][cb] = (f32x4){0.f, 0.f, 0.f, 0.f};

  for (int kk = 0; kk < 8; ++kk) {
    bf16x8 bfr[4];
    #pragma unroll
    for (int cb = 0; cb < 4; ++cb)
      bfr[cb] = *reinterpret_cast<const bf16x8*>(&xsb[cb * 16 + ll][kk * 32 + lg * 8]);
    #pragma unroll
    for (int j = 0; j < 3; ++j) {
      int rb = wave + j * 8;
      if (rb < 20) {
        bf16x8 afr = *reinterpret_cast<const bf16x8*>(
            wt + ((size_t)(rb * 16 + ll)) * 256 + kk * 32 + lg * 8);
        #pragma unroll
        for (int cb = 0; cb < 4; ++cb)
          acc[j][cb] = __builtin_amdgcn_mfma_f32_16x16x32_bf16(afr, bfr[cb], acc[j][cb], 0, 0, 0);
      }
    }
  }

  // ---- epilogue: + bias, write qt[b][n][32], kt[b][n][32], v[b][c][n]
  #pragma unroll
  for (int j = 0; j < 3; ++j) {
    int rb = wave + j * 8;
    if (rb < 20) {
      int row0 = rb * 16 + lg * 4;
      float4 b4 = *reinterpret_cast<const float4*>(bias + row0);
      #pragma unroll
      for (int cb = 0; cb < 4; ++cb) {
        int n = n0 + cb * 16 + ll;
        float v0 = acc[j][cb][0] + b4.x, v1 = acc[j][cb][1] + b4.y;
        float v2 = acc[j][cb][2] + b4.z, v3 = acc[j][cb][3] + b4.w;
        if (row0 < 32) {
          bf16x4 pk = {(bf16)v0, (bf16)v1, (bf16)v2, (bf16)v3};
          *reinterpret_cast<bf16x4*>(qt + ((size_t)(b * N_ + n)) * D_ + row0) = pk;
        } else if (row0 < 64) {
          bf16x4 pk = {(bf16)v0, (bf16)v1, (bf16)v2, (bf16)v3};
          *reinterpret_cast<bf16x4*>(kt + ((size_t)(b * N_ + n)) * D_ + row0 - 32) = pk;
        } else {
          int c = row0 - 64;
          v[((size_t)(b * 256 + c + 0)) * N_ + n] = (bf16)v0;
          v[((size_t)(b * 256 + c + 1)) * N_ + n] = (bf16)v1;
          v[((size_t)(b * 256 + c + 2)) * N_ + n] = (bf16)v2;
          v[((size_t)(b * 256 + c + 3)) * N_ + n] = (bf16)v3;
        }
      }
    }
  }
}

// ---------------- kernel 3: flash-style attention, bf16 MFMA, 8 waves/block.
// Block = 512 thr handles (b, 32 query tokens). Row-sum l accumulated in VALU
// during the exp loop (per-wave 32-col band), reduced via shfl_xor + LDS.
__global__ __launch_bounds__(512) void k_attn(const bf16* __restrict__ qt,
    const bf16* __restrict__ kt, const bf16* __restrict__ v,
    float* __restrict__ outs) {
  __shared__ bf16 p_s[32][264];          // P tile [tn][tm], +8 pad
  __shared__ float l_red[8][32];
  __shared__ float l_s[32];
  int tid = threadIdx.x, wave = tid >> 6, l = tid & 63;
  int lg = l >> 4, ll = l & 15;
  int blk = blockIdx.x;
  int b  = (blk & 7) >> 1;                       // XCD-pair -> batch (L2 locality)
  int nt = ((blk >> 3) << 1) | (blk & 1);
  int n0 = nt * 32;

  const f32x4 fz = {0.f, 0.f, 0.f, 0.f};

  // A-frags for QK^T (A = Q^T [32tn x 32d]): row = tn = ll, k = d = lg*8+e
  bf16x8 aq[2];
  #pragma unroll
  for (int tnf = 0; tnf < 2; ++tnf)
    aq[tnf] = *reinterpret_cast<const bf16x8*>(
        qt + ((size_t)(b * N_ + n0 + tnf * 16 + ll)) * D_ + lg * 8);

  f32x4 acc[2][2];   // [tnf][cf] : out tile [32tn x 32c per wave]
  float lsum[2][4];  // [tnf][r] row-sum partials (this wave's 32-col band)
  #pragma unroll
  for (int a = 0; a < 2; ++a) {
    #pragma unroll
    for (int cf = 0; cf < 2; ++cf) acc[a][cf] = fz;
    #pragma unroll
    for (int r = 0; r < 4; ++r) lsum[a][r] = 0.f;
  }

  const int mw = wave * 32;   // phase A: this wave's tm band
  const int cw = wave * 32;   // phase B: this wave's c band

  for (int t = 0; t < 16; ++t) {
    int m0 = t * 256;
    // ---- phase A: E = Q^T K for tm in [m0+mw, +32), write exp(E) to p_s
    #pragma unroll
    for (int tmf = 0; tmf < 2; ++tmf) {
      int mglob = m0 + mw + tmf * 16 + ll;
      bf16x8 bk8 = *reinterpret_cast<const bf16x8*>(
          kt + ((size_t)(b * N_ + mglob)) * D_ + lg * 8);
      #pragma unroll
      for (int tnf = 0; tnf < 2; ++tnf) {
        f32x4 e = __builtin_amdgcn_mfma_f32_16x16x32_bf16(aq[tnf], bk8, fz, 0, 0, 0);
        int col = mw + tmf * 16 + ll;   // D: row = tn = lg*4+r, col = tm = ll
        #pragma unroll
        for (int r = 0; r < 4; ++r) {
          float p = __expf(e[r]);
          lsum[tnf][r] += p;
          p_s[tnf * 16 + lg * 4 + r][col] = (bf16)p;
        }
      }
    }
    __syncthreads();
    // ---- phase B: O += P V^T ; A = P[32tn x 256tm] from LDS, B from global v
    #pragma unroll
    for (int kk = 0; kk < 8; ++kk) {
      bf16x8 pa[2];
      #pragma unroll
      for (int tnf = 0; tnf < 2; ++tnf)
        pa[tnf] = *reinterpret_cast<const bf16x8*>(
            &p_s[tnf * 16 + ll][kk * 32 + lg * 8]);
      #pragma unroll
      for (int cf = 0; cf < 2; ++cf) {
        int c = cw + cf * 16 + ll;
        bf16x8 bv8 = *reinterpret_cast<const bf16x8*>(
            v + ((size_t)((b << 8) + c)) * N_ + m0 + kk * 32 + lg * 8);
        acc[0][cf] = __builtin_amdgcn_mfma_f32_16x16x32_bf16(pa[0], bv8, acc[0][cf], 0, 0, 0);
        acc[1][cf] = __builtin_amdgcn_mfma_f32_16x16x32_bf16(pa[1], bv8, acc[1][cf], 0, 0, 0);
      }
    }
    __syncthreads();
  }

  // ---- reduce l: over 16 ll lanes (shfl), then over 8 waves (LDS)
  #pragma unroll
  for (int tnf = 0; tnf < 2; ++tnf) {
    #pragma unroll
    for (int r = 0; r < 4; ++r) {
      float s = lsum[tnf][r];
      s += __shfl_xor(s, 1);
      s += __shfl_xor(s, 2);
      s += __shfl_xor(s, 4);
      s += __shfl_xor(s, 8);
      if (ll == 0) l_red[wave][tnf * 16 + lg * 4 + r] = s;
    }
  }
  __syncthreads();
  if (tid < 32) {
    float s = 0.f;
    #pragma unroll
    for (int w = 0; w < 8; ++w) s += l_red[w][tid];
    l_s[tid] = s;
  }
  __syncthreads();

  // ---- normalize + write outs[b][c][n]
  #pragma unroll
  for (int tnf = 0; tnf < 2; ++tnf) {
    #pragma unroll
    for (int r = 0; r < 4; ++r) {
      int tn = tnf * 16 + lg * 4 + r;
      float inv = 1.0f / l_s[tn];
      #pragma unroll
      for (int cf = 0; cf < 2; ++cf) {
        int c = cw + cf * 16 + ll;
        outs[((size_t)((b << 8) + c)) * N_ + n0 + tn] = acc[tnf][cf][r] * inv;
      }
    }
  }
}

// ---------------- kernel 4: bilinear upsample x4 (half-pixel) + gamma residual
__global__ __launch_bounds__(256) void k_up(const float* __restrict__ outs,
    const float* __restrict__ x, const float* __restrict__ gamma,
    float* __restrict__ out) {
  int j = blockIdx.x * 256 + threadIdx.x;
  int wq = j & 63, h = (j >> 6) & 255, bc = j >> 14;
  int th = 2 * h - 3;
  int h0 = th < 0 ? -1 : (th >> 3);
  float fh = (float)(th - 8 * h0) * 0.125f;
  int i0h = h0 < 0 ? 0 : h0;
  int i1h = h0 + 1 > 63 ? 63 : h0 + 1;
  const float* s0 = outs + ((size_t)(bc * 64 + i0h)) * 64;
  const float* s1 = outs + ((size_t)(bc * 64 + i1h)) * 64;
  float g = gamma[0];
  float r4[4];
  #pragma unroll
  for (int k2 = 0; k2 < 4; ++k2) {
    int w = wq * 4 + k2;
    int tw = 2 * w - 3;
    int w0 = tw < 0 ? -1 : (tw >> 3);
    float fw = (float)(tw - 8 * w0) * 0.125f;
    int i0 = w0 < 0 ? 0 : w0;
    int i1 = w0 + 1 > 63 ? 63 : w0 + 1;
    float a = s0[i0], bb = s0[i1], cc = s1[i0], dd = s1[i1];
    float top = a + fw * (bb - a);
    float bot = cc + fw * (dd - cc);
    r4[k2] = top + fh * (bot - top);
  }
  size_t o4 = (size_t)(bc * 256 + h) * 64 + wq;
  float4 xv = reinterpret_cast<const float4*>(x)[o4];
  float4 o;
  o.x = g * r4[0] + xv.x; o.y = g * r4[1] + xv.y;
  o.z = g * r4[2] + xv.z; o.w = g * r4[3] + xv.w;
  reinterpret_cast<float4*>(out)[o4] = o;
}

extern "C" void kernel_launch(void* const* d_in, const int* in_sizes, int n_in,
                              void* d_out, int out_size, void* d_ws, size_t ws_size,
                              hipStream_t stream) {
  const float* x     = (const float*)d_in[0];
  const float* Wq    = (const float*)d_in[1];
  const float* bq    = (const float*)d_in[2];
  const float* Wk    = (const float*)d_in[3];
  const float* bk    = (const float*)d_in[4];
  const float* Wv    = (const float*)d_in[5];
  const float* bv    = (const float*)d_in[6];
  const float* gamma = (const float*)d_in[7];
  float* out = (float*)d_out;

  char* ws = (char*)d_ws;
  float* outs = (float*)(ws);                         // 16 MiB
  bf16*  v    = (bf16*) (ws + (16u << 20));           // 8 MiB
  bf16*  qt   = (bf16*) (ws + (24u << 20));           // 1 MiB
  bf16*  kt   = (bf16*) (ws + (25u << 20));           // 1 MiB
  bf16*  wt   = (bf16*) (ws + (26u << 20));           // 160 KiB
  float* bias = (float*)(ws + (27u << 20));           // 1.25 KiB

  hipLaunchKernelGGL(k_prep,  dim3(320),   dim3(256), 0, stream,
                     Wq, bq, Wk, bk, Wv, bv, wt, bias);
  hipLaunchKernelGGL(k_fused, dim3(256),   dim3(512), 0, stream,
                     x, wt, bias, qt, kt, v);
  hipLaunchKernelGGL(k_attn,  dim3(512),   dim3(512), 0, stream, qt, kt, v, outs);
  hipLaunchKernelGGL(k_up,    dim3(65536), dim3(256), 0, stream, outs, x, gamma, out);
}

// Round 4
// 259.599 us; speedup vs baseline: 1.7072x; 1.1488x over previous
//
#include <hip/hip_runtime.h>

#define B_ 4
#define C_ 256
#define N_ 4096
#define D_ 32

typedef __bf16 bf16;
typedef __bf16 bf16x4 __attribute__((ext_vector_type(4)));
typedef __bf16 bf16x8 __attribute__((ext_vector_type(8)));
typedef float f32x4 __attribute__((ext_vector_type(4)));

// ---------------- kernel 0: weight prep — concat W,b to bf16 wt[320][256], f32 bias[320]
__global__ __launch_bounds__(256) void k_prep(
    const float* __restrict__ Wq, const float* __restrict__ bq,
    const float* __restrict__ Wk, const float* __restrict__ bk,
    const float* __restrict__ Wv, const float* __restrict__ bv,
    bf16* __restrict__ wt, float* __restrict__ bias) {
  int r = blockIdx.x, t = threadIdx.x;
  const float* src; float bval;
  if (r < 32)      { src = Wq + (r << 8);        bval = bq[r]; }
  else if (r < 64) { src = Wk + ((r - 32) << 8); bval = bk[r - 32]; }
  else             { src = Wv + ((r - 64) << 8); bval = bv[r - 64]; }
  wt[(r << 8) + t] = (bf16)src[t];
  if (t == 0) bias[r] = bval;
}

// ---------------- kernel 1: fused avgpool(4x4) + q/k/v 1x1-conv GEMM (MFMA)
// Block = 1024 thr (16 waves) handles (b, hp): 64 pooled tokens x 320 out rows.
__global__ __launch_bounds__(1024) void k_fused(const float* __restrict__ x,
    const bf16* __restrict__ wt, const float* __restrict__ bias,
    bf16* __restrict__ qt, bf16* __restrict__ kt, bf16* __restrict__ v) {
  __shared__ bf16 xsb[64][264];   // [n][c], +8 pad
  int tid = threadIdx.x, wave = tid >> 6, l = tid & 63;
  int lg = l >> 4, ll = l & 15;
  int b = blockIdx.x >> 6, hp = blockIdx.x & 63, n0 = hp * 64;

  // ---- phase 1: pool. wave w covers channels [w*16, +16); lane l = token wp.
  const float4* x4 = reinterpret_cast<const float4*>(x) +
      ((size_t)((b * 256 + wave * 16) * 256 + hp * 4)) * 64 + l;
  for (int c0 = 0; c0 < 16; c0 += 4) {
    float s[4] = {0.f, 0.f, 0.f, 0.f};
    #pragma unroll
    for (int j = 0; j < 4; ++j) {
      const float4* p = x4 + (size_t)(c0 + j) * 16384;
      #pragma unroll
      for (int dh = 0; dh < 4; ++dh) {
        float4 a = p[dh * 64];
        s[j] += a.x + a.y + a.z + a.w;
      }
    }
    bf16x4 pk;
    #pragma unroll
    for (int j = 0; j < 4; ++j) pk[j] = (bf16)(s[j] * 0.0625f);
    *reinterpret_cast<bf16x4*>(&xsb[l][wave * 16 + c0]) = pk;
  }
  __syncthreads();

  // ---- phase 2: GEMM D[320 rows][64 n] = wt * xsb, K=256.
  // 20 rowblocks of 16; wave w owns rb = w and (w<4) 16+w.
  f32x4 acc[2][4];
  #pragma unroll
  for (int j = 0; j < 2; ++j)
    #pragma unroll
    for (int cb = 0; cb < 4; ++cb) acc[j][cb] = (f32x4){0.f, 0.f, 0.f, 0.f};

  for (int kk = 0; kk < 8; ++kk) {
    bf16x8 bfr[4];
    #pragma unroll
    for (int cb = 0; cb < 4; ++cb)
      bfr[cb] = *reinterpret_cast<const bf16x8*>(&xsb[cb * 16 + ll][kk * 32 + lg * 8]);
    #pragma unroll
    for (int j = 0; j < 2; ++j) {
      int rb = wave + j * 16;
      if (rb < 20) {
        bf16x8 afr = *reinterpret_cast<const bf16x8*>(
            wt + ((size_t)(rb * 16 + ll)) * 256 + kk * 32 + lg * 8);
        #pragma unroll
        for (int cb = 0; cb < 4; ++cb)
          acc[j][cb] = __builtin_amdgcn_mfma_f32_16x16x32_bf16(afr, bfr[cb], acc[j][cb], 0, 0, 0);
      }
    }
  }

  // ---- epilogue: + bias, write qt[b][n][32], kt[b][n][32], v[b][c][n]
  #pragma unroll
  for (int j = 0; j < 2; ++j) {
    int rb = wave + j * 16;
    if (rb < 20) {
      int row0 = rb * 16 + lg * 4;
      float4 b4 = *reinterpret_cast<const float4*>(bias + row0);
      #pragma unroll
      for (int cb = 0; cb < 4; ++cb) {
        int n = n0 + cb * 16 + ll;
        float v0 = acc[j][cb][0] + b4.x, v1 = acc[j][cb][1] + b4.y;
        float v2 = acc[j][cb][2] + b4.z, v3 = acc[j][cb][3] + b4.w;
        if (row0 < 32) {
          bf16x4 pk = {(bf16)v0, (bf16)v1, (bf16)v2, (bf16)v3};
          *reinterpret_cast<bf16x4*>(qt + ((size_t)(b * N_ + n)) * D_ + row0) = pk;
        } else if (row0 < 64) {
          bf16x4 pk = {(bf16)v0, (bf16)v1, (bf16)v2, (bf16)v3};
          *reinterpret_cast<bf16x4*>(kt + ((size_t)(b * N_ + n)) * D_ + row0 - 32) = pk;
        } else {
          int c = row0 - 64;
          v[((size_t)(b * 256 + c + 0)) * N_ + n] = (bf16)v0;
          v[((size_t)(b * 256 + c + 1)) * N_ + n] = (bf16)v1;
          v[((size_t)(b * 256 + c + 2)) * N_ + n] = (bf16)v2;
          v[((size_t)(b * 256 + c + 3)) * N_ + n] = (bf16)v3;
        }
      }
    }
  }
}

// ---------------- kernel 3: flash-style attention, bf16 MFMA.
// Block = 1024 thr (16 waves) handles (b, 64 query tokens). QBLK=64.
// Wave w: phase A computes E cols [w*16,+16) for all 64 rows; phase B covers
// c band [w*16,+16). Row-sum in VALU during exp, reduced shfl+LDS.
__global__ __launch_bounds__(1024) void k_attn(const bf16* __restrict__ qt,
    const bf16* __restrict__ kt, const bf16* __restrict__ v,
    float* __restrict__ outs) {
  __shared__ bf16 p_s[64][264];          // P tile [tn][tm], +8 pad
  __shared__ float l_red[16][64];
  __shared__ float l_s[64];
  int tid = threadIdx.x, wave = tid >> 6, l = tid & 63;
  int lg = l >> 4, ll = l & 15;
  int blk = blockIdx.x;
  int b  = (blk & 7) >> 1;                       // XCD-pair -> batch (L2 locality)
  int nt = ((blk >> 3) << 1) | (blk & 1);        // 64 query tiles of 64
  int n0 = nt * 64;

  const f32x4 fz = {0.f, 0.f, 0.f, 0.f};

  // A-frags for QK^T: row = tn = ll (within tnf block), k = d = lg*8+e
  bf16x8 aq[4];
  #pragma unroll
  for (int tnf = 0; tnf < 4; ++tnf)
    aq[tnf] = *reinterpret_cast<const bf16x8*>(
        qt + ((size_t)(b * N_ + n0 + tnf * 16 + ll)) * D_ + lg * 8);

  f32x4 acc[4];      // [tnf] : out tile [64tn x 16c per wave]
  float lsum[4][4];  // [tnf][r] row-sum partials (this wave's 16-col band)
  #pragma unroll
  for (int a = 0; a < 4; ++a) {
    acc[a] = fz;
    #pragma unroll
    for (int r = 0; r < 4; ++r) lsum[a][r] = 0.f;
  }

  const int mw = wave * 16;   // phase A tm band == phase B c band
  for (int t = 0; t < 16; ++t) {
    int m0 = t * 256;
    // ---- phase A: E = Q^T K for tm in [m0+mw, +16), write exp(E) to p_s
    {
      int mglob = m0 + mw + ll;
      bf16x8 bk8 = *reinterpret_cast<const bf16x8*>(
          kt + ((size_t)(b * N_ + mglob)) * D_ + lg * 8);
      #pragma unroll
      for (int tnf = 0; tnf < 4; ++tnf) {
        f32x4 e = __builtin_amdgcn_mfma_f32_16x16x32_bf16(aq[tnf], bk8, fz, 0, 0, 0);
        int col = mw + ll;   // D: row = lg*4+r, col = ll
        #pragma unroll
        for (int r = 0; r < 4; ++r) {
          float p = __expf(e[r]);
          lsum[tnf][r] += p;
          p_s[tnf * 16 + lg * 4 + r][col] = (bf16)p;
        }
      }
    }
    __syncthreads();
    // ---- phase B: O += P V^T ; A = P from LDS, B from global v (L2-resident)
    #pragma unroll
    for (int kk = 0; kk < 8; ++kk) {
      bf16x8 bv8 = *reinterpret_cast<const bf16x8*>(
          v + ((size_t)((b << 8) + mw + ll)) * N_ + m0 + kk * 32 + lg * 8);
      #pragma unroll
      for (int tnf = 0; tnf < 4; ++tnf) {
        bf16x8 pa = *reinterpret_cast<const bf16x8*>(
            &p_s[tnf * 16 + ll][kk * 32 + lg * 8]);
        acc[tnf] = __builtin_amdgcn_mfma_f32_16x16x32_bf16(pa, bv8, acc[tnf], 0, 0, 0);
      }
    }
    __syncthreads();
  }

  // ---- reduce l: over 16 ll lanes (shfl), then over 16 waves (LDS)
  #pragma unroll
  for (int tnf = 0; tnf < 4; ++tnf) {
    #pragma unroll
    for (int r = 0; r < 4; ++r) {
      float s = lsum[tnf][r];
      s += __shfl_xor(s, 1);
      s += __shfl_xor(s, 2);
      s += __shfl_xor(s, 4);
      s += __shfl_xor(s, 8);
      if (ll == 0) l_red[wave][tnf * 16 + lg * 4 + r] = s;
    }
  }
  __syncthreads();
  if (tid < 64) {
    float s = 0.f;
    #pragma unroll
    for (int w = 0; w < 16; ++w) s += l_red[w][tid];
    l_s[tid] = s;
  }
  __syncthreads();

  // ---- normalize + write outs[b][c][n] (float4 over contiguous n)
  int c = mw + ll;
  #pragma unroll
  for (int tnf = 0; tnf < 4; ++tnf) {
    int tn0 = tnf * 16 + lg * 4;
    float4 o;
    o.x = acc[tnf][0] / l_s[tn0 + 0];
    o.y = acc[tnf][1] / l_s[tn0 + 1];
    o.z = acc[tnf][2] / l_s[tn0 + 2];
    o.w = acc[tnf][3] / l_s[tn0 + 3];
    *reinterpret_cast<float4*>(outs + ((size_t)((b << 8) + c)) * N_ + n0 + tn0) = o;
  }
}

// ---------------- kernel 4: bilinear upsample x4 + gamma residual.
// Block = 256 thr handles one (b,c) slice: outs[bc] (16KB) staged in LDS,
// each wave emits one 256-wide output row per iter (float4 I/O).
__global__ __launch_bounds__(256) void k_up(const float* __restrict__ outs,
    const float* __restrict__ x, const float* __restrict__ gamma,
    float* __restrict__ out) {
  __shared__ float s_o[4096];            // outs[bc] as [64][64]
  int tid = threadIdx.x, wave = tid >> 6, tw = tid & 63;
  int bc = blockIdx.x;
  const float* src = outs + (size_t)bc * 4096;
  #pragma unroll
  for (int ch = 0; ch < 4; ++ch)
    *reinterpret_cast<float4*>(&s_o[ch * 1024 + tid * 4]) =
        *reinterpret_cast<const float4*>(src + ch * 1024 + tid * 4);
  __syncthreads();

  float g = gamma[0];
  const float4* xr = reinterpret_cast<const float4*>(x) + (size_t)bc * 16384;
  float4* outr = reinterpret_cast<float4*>(out) + (size_t)bc * 16384;

  int twm = tw == 0 ? 0 : tw - 1;
  int twp = tw == 63 ? 63 : tw + 1;

  for (int hb = 0; hb < 64; ++hb) {
    int h = hb * 4 + wave;
    int th = 2 * h - 3;
    int h0 = th < 0 ? -1 : (th >> 3);
    float fh = (float)(th - 8 * h0) * 0.125f;
    int i0h = h0 < 0 ? 0 : h0;
    int i1h = h0 + 1 > 63 ? 63 : h0 + 1;
    const float* r0 = &s_o[i0h * 64];
    const float* r1 = &s_o[i1h * 64];
    float a_m = r0[twm], a_c = r0[tw], a_p = r0[twp];
    float b_m = r1[twm], b_c = r1[tw], b_p = r1[twp];
    // w-interp with constant weights: k2=0: m..c @0.625; 1: @0.875; 2: c..p @0.125; 3: @0.375
    float t0 = a_m + 0.625f * (a_c - a_m), u0 = b_m + 0.625f * (b_c - b_m);
    float t1 = a_m + 0.875f * (a_c - a_m), u1 = b_m + 0.875f * (b_c - b_m);
    float t2 = a_c + 0.125f * (a_p - a_c), u2 = b_c + 0.125f * (b_p - b_c);
    float t3 = a_c + 0.375f * (a_p - a_c), u3 = b_c + 0.375f * (b_p - b_c);
    float4 xv = xr[h * 64 + tw];
    float4 o;
    o.x = g * (t0 + fh * (u0 - t0)) + xv.x;
    o.y = g * (t1 + fh * (u1 - t1)) + xv.y;
    o.z = g * (t2 + fh * (u2 - t2)) + xv.z;
    o.w = g * (t3 + fh * (u3 - t3)) + xv.w;
    outr[h * 64 + tw] = o;
  }
}

extern "C" void kernel_launch(void* const* d_in, const int* in_sizes, int n_in,
                              void* d_out, int out_size, void* d_ws, size_t ws_size,
                              hipStream_t stream) {
  const float* x     = (const float*)d_in[0];
  const float* Wq    = (const float*)d_in[1];
  const float* bq    = (const float*)d_in[2];
  const float* Wk    = (const float*)d_in[3];
  const float* bk    = (const float*)d_in[4];
  const float* Wv    = (const float*)d_in[5];
  const float* bv    = (const float*)d_in[6];
  const float* gamma = (const float*)d_in[7];
  float* out = (float*)d_out;

  char* ws = (char*)d_ws;
  float* outs = (float*)(ws);                         // 16 MiB
  bf16*  v    = (bf16*) (ws + (16u << 20));           // 8 MiB
  bf16*  qt   = (bf16*) (ws + (24u << 20));           // 1 MiB
  bf16*  kt   = (bf16*) (ws + (25u << 20));           // 1 MiB
  bf16*  wt   = (bf16*) (ws + (26u << 20));           // 160 KiB
  float* bias = (float*)(ws + (27u << 20));           // 1.25 KiB

  hipLaunchKernelGGL(k_prep,  dim3(320),  dim3(256),  0, stream,
                     Wq, bq, Wk, bk, Wv, bv, wt, bias);
  hipLaunchKernelGGL(k_fused, dim3(256),  dim3(1024), 0, stream,
                     x, wt, bias, qt, kt, v);
  hipLaunchKernelGGL(k_attn,  dim3(256),  dim3(1024), 0, stream, qt, kt, v, outs);
  hipLaunchKernelGGL(k_up,    dim3(1024), dim3(256),  0, stream, outs, x, gamma, out);
}

// Round 5
// 253.137 us; speedup vs baseline: 1.7508x; 1.0255x over previous
//
#include <hip/hip_runtime.h>

#define B_ 4
#define C_ 256
#define N_ 4096
#define D_ 32

typedef __bf16 bf16;
typedef __bf16 bf16x4 __attribute__((ext_vector_type(4)));
typedef __bf16 bf16x8 __attribute__((ext_vector_type(8)));
typedef float f32x4 __attribute__((ext_vector_type(4)));

// ---------------- kernel 0: weight prep — concat W,b to bf16 wt[320][256], f32 bias[320]
__global__ __launch_bounds__(256) void k_prep(
    const float* __restrict__ Wq, const float* __restrict__ bq,
    const float* __restrict__ Wk, const float* __restrict__ bk,
    const float* __restrict__ Wv, const float* __restrict__ bv,
    bf16* __restrict__ wt, float* __restrict__ bias) {
  int r = blockIdx.x, t = threadIdx.x;
  const float* src; float bval;
  if (r < 32)      { src = Wq + (r << 8);        bval = bq[r]; }
  else if (r < 64) { src = Wk + ((r - 32) << 8); bval = bk[r - 32]; }
  else             { src = Wv + ((r - 64) << 8); bval = bv[r - 64]; }
  wt[(r << 8) + t] = (bf16)src[t];
  if (t == 0) bias[r] = bval;
}

// ---------------- kernel 1: fused avgpool(4x4) + q/k/v 1x1-conv GEMM (MFMA)
// Block = 1024 thr (16 waves) handles (b, hp): 64 pooled tokens x 320 out rows.
__global__ __launch_bounds__(1024) void k_fused(const float* __restrict__ x,
    const bf16* __restrict__ wt, const float* __restrict__ bias,
    bf16* __restrict__ qt, bf16* __restrict__ kt, bf16* __restrict__ v) {
  __shared__ bf16 xsb[64][264];   // [n][c], +8 pad
  int tid = threadIdx.x, wave = tid >> 6, l = tid & 63;
  int lg = l >> 4, ll = l & 15;
  int b = blockIdx.x >> 6, hp = blockIdx.x & 63, n0 = hp * 64;

  // ---- phase 1: pool. wave w covers channels [w*16, +16); lane l = token wp.
  const float4* x4 = reinterpret_cast<const float4*>(x) +
      ((size_t)((b * 256 + wave * 16) * 256 + hp * 4)) * 64 + l;
  for (int c0 = 0; c0 < 16; c0 += 4) {
    float s[4] = {0.f, 0.f, 0.f, 0.f};
    #pragma unroll
    for (int j = 0; j < 4; ++j) {
      const float4* p = x4 + (size_t)(c0 + j) * 16384;
      #pragma unroll
      for (int dh = 0; dh < 4; ++dh) {
        float4 a = p[dh * 64];
        s[j] += a.x + a.y + a.z + a.w;
      }
    }
    bf16x4 pk;
    #pragma unroll
    for (int j = 0; j < 4; ++j) pk[j] = (bf16)(s[j] * 0.0625f);
    *reinterpret_cast<bf16x4*>(&xsb[l][wave * 16 + c0]) = pk;
  }
  __syncthreads();

  // ---- phase 2: GEMM D[320 rows][64 n] = wt * xsb, K=256.
  f32x4 acc[2][4];
  #pragma unroll
  for (int j = 0; j < 2; ++j)
    #pragma unroll
    for (int cb = 0; cb < 4; ++cb) acc[j][cb] = (f32x4){0.f, 0.f, 0.f, 0.f};

  for (int kk = 0; kk < 8; ++kk) {
    bf16x8 bfr[4];
    #pragma unroll
    for (int cb = 0; cb < 4; ++cb)
      bfr[cb] = *reinterpret_cast<const bf16x8*>(&xsb[cb * 16 + ll][kk * 32 + lg * 8]);
    #pragma unroll
    for (int j = 0; j < 2; ++j) {
      int rb = wave + j * 16;
      if (rb < 20) {
        bf16x8 afr = *reinterpret_cast<const bf16x8*>(
            wt + ((size_t)(rb * 16 + ll)) * 256 + kk * 32 + lg * 8);
        #pragma unroll
        for (int cb = 0; cb < 4; ++cb)
          acc[j][cb] = __builtin_amdgcn_mfma_f32_16x16x32_bf16(afr, bfr[cb], acc[j][cb], 0, 0, 0);
      }
    }
  }

  // ---- epilogue: + bias, write qt[b][n][32], kt[b][n][32], v[b][c][n]
  #pragma unroll
  for (int j = 0; j < 2; ++j) {
    int rb = wave + j * 16;
    if (rb < 20) {
      int row0 = rb * 16 + lg * 4;
      float4 b4 = *reinterpret_cast<const float4*>(bias + row0);
      #pragma unroll
      for (int cb = 0; cb < 4; ++cb) {
        int n = n0 + cb * 16 + ll;
        float v0 = acc[j][cb][0] + b4.x, v1 = acc[j][cb][1] + b4.y;
        float v2 = acc[j][cb][2] + b4.z, v3 = acc[j][cb][3] + b4.w;
        if (row0 < 32) {
          bf16x4 pk = {(bf16)v0, (bf16)v1, (bf16)v2, (bf16)v3};
          *reinterpret_cast<bf16x4*>(qt + ((size_t)(b * N_ + n)) * D_ + row0) = pk;
        } else if (row0 < 64) {
          bf16x4 pk = {(bf16)v0, (bf16)v1, (bf16)v2, (bf16)v3};
          *reinterpret_cast<bf16x4*>(kt + ((size_t)(b * N_ + n)) * D_ + row0 - 32) = pk;
        } else {
          int c = row0 - 64;
          v[((size_t)(b * 256 + c + 0)) * N_ + n] = (bf16)v0;
          v[((size_t)(b * 256 + c + 1)) * N_ + n] = (bf16)v1;
          v[((size_t)(b * 256 + c + 2)) * N_ + n] = (bf16)v2;
          v[((size_t)(b * 256 + c + 3)) * N_ + n] = (bf16)v3;
        }
      }
    }
  }
}

// ---------------- kernel 3: flash-style attention, bf16 MFMA, double-buffered.
// Block = 1024 thr (16 waves) handles (b, 64 query tokens). One barrier/iter:
// iter t interleaves PV(t) from p_s[cur] with QK^T/exp(t+1) into p_s[nxt].
__global__ __launch_bounds__(1024) void k_attn(const bf16* __restrict__ qt,
    const bf16* __restrict__ kt, const bf16* __restrict__ v,
    float* __restrict__ outs) {
  __shared__ bf16 p_s[2][64][264];       // 2 x (P tile [tn][tm], +8 pad)
  __shared__ float l_red[16][64];
  __shared__ float l_s[64];
  int tid = threadIdx.x, wave = tid >> 6, l = tid & 63;
  int lg = l >> 4, ll = l & 15;
  int blk = blockIdx.x;
  int b  = (blk & 7) >> 1;                       // XCD-pair -> batch (L2 locality)
  int nt = ((blk >> 3) << 1) | (blk & 1);        // 64 query tiles of 64
  int n0 = nt * 64;

  const f32x4 fz = {0.f, 0.f, 0.f, 0.f};

  bf16x8 aq[4];
  #pragma unroll
  for (int tnf = 0; tnf < 4; ++tnf)
    aq[tnf] = *reinterpret_cast<const bf16x8*>(
        qt + ((size_t)(b * N_ + n0 + tnf * 16 + ll)) * D_ + lg * 8);

  f32x4 acc[4];      // [tnf] : out tile [64tn x 16c per wave]
  float lsum[4][4];  // [tnf][r] row-sum partials
  #pragma unroll
  for (int a = 0; a < 4; ++a) {
    acc[a] = fz;
    #pragma unroll
    for (int r = 0; r < 4; ++r) lsum[a][r] = 0.f;
  }

  const int mw = wave * 16;   // QK^T tm band == PV c band
  const int colw = mw + ll;

  // ---- prologue: A(0) into p_s[0]
  {
    bf16x8 bk8 = *reinterpret_cast<const bf16x8*>(
        kt + ((size_t)(b * N_ + colw)) * D_ + lg * 8);
    #pragma unroll
    for (int tnf = 0; tnf < 4; ++tnf) {
      f32x4 e = __builtin_amdgcn_mfma_f32_16x16x32_bf16(aq[tnf], bk8, fz, 0, 0, 0);
      #pragma unroll
      for (int r = 0; r < 4; ++r) {
        float p = __expf(e[r]);
        lsum[tnf][r] += p;
        p_s[0][tnf * 16 + lg * 4 + r][colw] = (bf16)p;
      }
    }
  }
  __syncthreads();

  // ---- main loop: B(t) || A(t+1), one barrier per iter
  for (int t = 0; t < 15; ++t) {
    int m0 = t * 256;
    int cur = t & 1, nxt = cur ^ 1;
    // A(t+1) kt load issued first (covered by B's MFMA stream)
    bf16x8 bk8 = *reinterpret_cast<const bf16x8*>(
        kt + ((size_t)(b * N_ + m0 + 256 + colw)) * D_ + lg * 8);
    // B(t): O += P V^T from p_s[cur]
    #pragma unroll
    for (int kk = 0; kk < 8; ++kk) {
      bf16x8 bv8 = *reinterpret_cast<const bf16x8*>(
          v + ((size_t)((b << 8) + colw)) * N_ + m0 + kk * 32 + lg * 8);
      #pragma unroll
      for (int tnf = 0; tnf < 4; ++tnf) {
        bf16x8 pa = *reinterpret_cast<const bf16x8*>(
            &p_s[cur][tnf * 16 + ll][kk * 32 + lg * 8]);
        acc[tnf] = __builtin_amdgcn_mfma_f32_16x16x32_bf16(pa, bv8, acc[tnf], 0, 0, 0);
      }
    }
    // A(t+1): E -> exp -> p_s[nxt]
    #pragma unroll
    for (int tnf = 0; tnf < 4; ++tnf) {
      f32x4 e = __builtin_amdgcn_mfma_f32_16x16x32_bf16(aq[tnf], bk8, fz, 0, 0, 0);
      #pragma unroll
      for (int r = 0; r < 4; ++r) {
        float p = __expf(e[r]);
        lsum[tnf][r] += p;
        p_s[nxt][tnf * 16 + lg * 4 + r][colw] = (bf16)p;
      }
    }
    __syncthreads();
  }
  // ---- tail: B(15) from p_s[1]
  {
    int m0 = 15 * 256;
    #pragma unroll
    for (int kk = 0; kk < 8; ++kk) {
      bf16x8 bv8 = *reinterpret_cast<const bf16x8*>(
          v + ((size_t)((b << 8) + colw)) * N_ + m0 + kk * 32 + lg * 8);
      #pragma unroll
      for (int tnf = 0; tnf < 4; ++tnf) {
        bf16x8 pa = *reinterpret_cast<const bf16x8*>(
            &p_s[1][tnf * 16 + ll][kk * 32 + lg * 8]);
        acc[tnf] = __builtin_amdgcn_mfma_f32_16x16x32_bf16(pa, bv8, acc[tnf], 0, 0, 0);
      }
    }
  }

  // ---- reduce l: over 16 ll lanes (shfl), then over 16 waves (LDS)
  #pragma unroll
  for (int tnf = 0; tnf < 4; ++tnf) {
    #pragma unroll
    for (int r = 0; r < 4; ++r) {
      float s = lsum[tnf][r];
      s += __shfl_xor(s, 1);
      s += __shfl_xor(s, 2);
      s += __shfl_xor(s, 4);
      s += __shfl_xor(s, 8);
      if (ll == 0) l_red[wave][tnf * 16 + lg * 4 + r] = s;
    }
  }
  __syncthreads();
  if (tid < 64) {
    float s = 0.f;
    #pragma unroll
    for (int w = 0; w < 16; ++w) s += l_red[w][tid];
    l_s[tid] = s;
  }
  __syncthreads();

  // ---- normalize + write outs[b][c][n] (float4 over contiguous n)
  #pragma unroll
  for (int tnf = 0; tnf < 4; ++tnf) {
    int tn0 = tnf * 16 + lg * 4;
    float4 o;
    o.x = acc[tnf][0] / l_s[tn0 + 0];
    o.y = acc[tnf][1] / l_s[tn0 + 1];
    o.z = acc[tnf][2] / l_s[tn0 + 2];
    o.w = acc[tnf][3] / l_s[tn0 + 3];
    *reinterpret_cast<float4*>(outs + ((size_t)((b << 8) + colw)) * N_ + n0 + tn0) = o;
  }
}

// ---------------- kernel 4: bilinear upsample x4 + gamma residual.
__global__ __launch_bounds__(256) void k_up(const float* __restrict__ outs,
    const float* __restrict__ x, const float* __restrict__ gamma,
    float* __restrict__ out) {
  __shared__ float s_o[4096];            // outs[bc] as [64][64]
  int tid = threadIdx.x, wave = tid >> 6, tw = tid & 63;
  int bc = blockIdx.x;
  const float* src = outs + (size_t)bc * 4096;
  #pragma unroll
  for (int ch = 0; ch < 4; ++ch)
    *reinterpret_cast<float4*>(&s_o[ch * 1024 + tid * 4]) =
        *reinterpret_cast<const float4*>(src + ch * 1024 + tid * 4);
  __syncthreads();

  float g = gamma[0];
  const float4* xr = reinterpret_cast<const float4*>(x) + (size_t)bc * 16384;
  float4* outr = reinterpret_cast<float4*>(out) + (size_t)bc * 16384;

  int twm = tw == 0 ? 0 : tw - 1;
  int twp = tw == 63 ? 63 : tw + 1;

  for (int hb = 0; hb < 64; ++hb) {
    int h = hb * 4 + wave;
    int th = 2 * h - 3;
    int h0 = th < 0 ? -1 : (th >> 3);
    float fh = (float)(th - 8 * h0) * 0.125f;
    int i0h = h0 < 0 ? 0 : h0;
    int i1h = h0 + 1 > 63 ? 63 : h0 + 1;
    const float* r0 = &s_o[i0h * 64];
    const float* r1 = &s_o[i1h * 64];
    float a_m = r0[twm], a_c = r0[tw], a_p = r0[twp];
    float b_m = r1[twm], b_c = r1[tw], b_p = r1[twp];
    float t0 = a_m + 0.625f * (a_c - a_m), u0 = b_m + 0.625f * (b_c - b_m);
    float t1 = a_m + 0.875f * (a_c - a_m), u1 = b_m + 0.875f * (b_c - b_m);
    float t2 = a_c + 0.125f * (a_p - a_c), u2 = b_c + 0.125f * (b_p - b_c);
    float t3 = a_c + 0.375f * (a_p - a_c), u3 = b_c + 0.375f * (b_p - b_c);
    float4 xv = xr[h * 64 + tw];
    float4 o;
    o.x = g * (t0 + fh * (u0 - t0)) + xv.x;
    o.y = g * (t1 + fh * (u1 - t1)) + xv.y;
    o.z = g * (t2 + fh * (u2 - t2)) + xv.z;
    o.w = g * (t3 + fh * (u3 - t3)) + xv.w;
    outr[h * 64 + tw] = o;
  }
}

extern "C" void kernel_launch(void* const* d_in, const int* in_sizes, int n_in,
                              void* d_out, int out_size, void* d_ws, size_t ws_size,
                              hipStream_t stream) {
  const float* x     = (const float*)d_in[0];
  const float* Wq    = (const float*)d_in[1];
  const float* bq    = (const float*)d_in[2];
  const float* Wk    = (const float*)d_in[3];
  const float* bk    = (const float*)d_in[4];
  const float* Wv    = (const float*)d_in[5];
  const float* bv    = (const float*)d_in[6];
  const float* gamma = (const float*)d_in[7];
  float* out = (float*)d_out;

  char* ws = (char*)d_ws;
  float* outs = (float*)(ws);                         // 16 MiB
  bf16*  v    = (bf16*) (ws + (16u << 20));           // 8 MiB
  bf16*  qt   = (bf16*) (ws + (24u << 20));           // 1 MiB
  bf16*  kt   = (bf16*) (ws + (25u << 20));           // 1 MiB
  bf16*  wt   = (bf16*) (ws + (26u << 20));           // 160 KiB
  float* bias = (float*)(ws + (27u << 20));           // 1.25 KiB

  hipLaunchKernelGGL(k_prep,  dim3(320),  dim3(256),  0, stream,
                     Wq, bq, Wk, bk, Wv, bv, wt, bias);
  hipLaunchKernelGGL(k_fused, dim3(256),  dim3(1024), 0, stream,
                     x, wt, bias, qt, kt, v);
  hipLaunchKernelGGL(k_attn,  dim3(256),  dim3(1024), 0, stream, qt, kt, v, outs);
  hipLaunchKernelGGL(k_up,    dim3(1024), dim3(256),  0, stream, outs, x, gamma, out);
}